// Round 6
// baseline (660.467 us; speedup 1.0000x reference)
//
#include <hip/hip_runtime.h>
#include <math.h>

#define B_ 4
#define T_ 4096
#define D_ 1024
#define H_ 16
#define DH_ 64
#define M_ (B_*T_)      // 16384
#define HD_ (H_*DH_)    // 1024
#define NB_ 1152        // B rows for gemm_v: 1024 V cols + 32 qk cols + 96 pad
#define NC_ 64
#define CS_ 64
#define PI_4 0.78539816339744830962f
#define EPS_ 1e-6f

typedef short bf16x8 __attribute__((ext_vector_type(8)));
typedef float f32x4 __attribute__((ext_vector_type(4)));

// round-to-nearest-even f32 -> bf16, no header dependency
static __device__ __forceinline__ unsigned short f2bf(float f) {
    unsigned u = __builtin_bit_cast(unsigned, f);
    unsigned rounding = 0x7fffu + ((u >> 16) & 1u);
    return (unsigned short)((u + rounding) >> 16);
}

#define GLDS16(gsrc, ldst) \
    __builtin_amdgcn_global_load_lds((const __attribute__((address_space(1))) void*)(gsrc), \
                                     (__attribute__((address_space(3))) void*)(ldst), 16, 0, 0)

// ---------------- converts ----------------
__global__ __launch_bounds__(256) void conv_a(const float* __restrict__ in,
                                              unsigned short* __restrict__ out) {
    int i = blockIdx.x * 256 + threadIdx.x;          // over 4M float4s
    float4 v = ((const float4*)in)[i];
    ushort4 o;
    o.x = f2bf(v.x); o.y = f2bf(v.y); o.z = f2bf(v.z); o.w = f2bf(v.w);
    ((ushort4*)out)[i] = o;
}

// Wv_bt[(h*64+e)*1024 + k] = WV[h*65536 + k*64 + e]   (rows 0..1023)
__global__ __launch_bounds__(256) void conv_wv(const float* __restrict__ WV,
                                               unsigned short* __restrict__ Bt) {
    int f = blockIdx.x * 256 + threadIdx.x;          // 1M
    int n = f >> 10, k = f & 1023;
    int h = n >> 6, e = n & 63;
    Bt[f] = f2bf(WV[h * 65536 + k * 64 + e]);
}

// rows 1024..1055 of Bt_v: 16 W_Q columns then 16 W_K columns
__global__ __launch_bounds__(256) void conv_wqk(const float* __restrict__ WQ,
                                                const float* __restrict__ WK,
                                                unsigned short* __restrict__ Bt) {
    int f = blockIdx.x * 256 + threadIdx.x;          // 32K
    int row = f >> 10, k = f & 1023;
    float v = (row < 16) ? WQ[row * 1024 + k] : WK[(row - 16) * 1024 + k];
    Bt[(size_t)(1024 + row) * 1024 + k] = f2bf(v);
}

// Wo_bt[d*1024 + h*64 + e] = WO[d*1024 + e*16 + h]
__global__ __launch_bounds__(256) void conv_wo(const float* __restrict__ WO,
                                               unsigned short* __restrict__ Bt) {
    int f = blockIdx.x * 256 + threadIdx.x;          // 1M
    int d = f >> 10, rem = f & 1023;
    int h = rem >> 6, e = rem & 63;
    Bt[f] = f2bf(WO[d * 1024 + e * 16 + h]);
}

// ---------------- bf16 MFMA GEMM core (m97 structure) ----------------
// C = A[M,K=1024] x B (Bt[n][k] transposed layout), 128x128 tile, BK=32.
// OUT_MODE 0: n<1024 -> Vt[b,h,t,e]; 1024<=n<1056 -> tanh/cos/sin -> cq/sq/ck/sk.
// OUT_MODE 1: store to Out[m*1024+n].
template <int OUT_MODE>
__global__ __launch_bounds__(256) void gemm_bf16(const unsigned short* __restrict__ A,
                                                 const unsigned short* __restrict__ Bt,
                                                 float* __restrict__ Out,
                                                 float* __restrict__ cq, float* __restrict__ sq,
                                                 float* __restrict__ ck, float* __restrict__ sk) {
    __shared__ short As[128 * 32];
    __shared__ short Bs[128 * 32];
    const int K = 1024;
    int tid = threadIdx.x;
    int m0 = blockIdx.x * 128;
    int n0 = blockIdx.y * 128;
    int lane = tid & 63, w = tid >> 6;
    int wm = (w >> 1) * 64, wn = (w & 1) * 64;
    int r = lane & 15, g = lane >> 4;

    int srow = tid >> 2;            // 0..63 staged row within a round
    int skq  = (tid & 3) * 8;       // k offset (8 bf16 = 16B)

    f32x4 acc[4][4];
#pragma unroll
    for (int i = 0; i < 4; ++i)
#pragma unroll
        for (int j = 0; j < 4; ++j) acc[i][j] = (f32x4)0.f;

    const unsigned short* gA = A  + (size_t)(m0 + srow) * K + skq;
    const unsigned short* gB = Bt + (size_t)(n0 + srow) * K + skq;
    char* lA = (char*)As + tid * 16;
    char* lB = (char*)Bs + tid * 16;

    for (int k0 = 0; k0 < K; k0 += 32) {
        GLDS16(gA + k0,            lA);
        GLDS16(gA + k0 + 64 * K,   lA + 4096);
        GLDS16(gB + k0,            lB);
        GLDS16(gB + k0 + 64 * K,   lB + 4096);
        __syncthreads();

        bf16x8 af[4], bf[4];
#pragma unroll
        for (int i = 0; i < 4; ++i)
            af[i] = *(const bf16x8*)&As[(wm + i * 16 + r) * 32 + g * 8];
#pragma unroll
        for (int j = 0; j < 4; ++j)
            bf[j] = *(const bf16x8*)&Bs[(wn + j * 16 + r) * 32 + g * 8];
#pragma unroll
        for (int i = 0; i < 4; ++i)
#pragma unroll
            for (int j = 0; j < 4; ++j)
                acc[i][j] = __builtin_amdgcn_mfma_f32_16x16x32_bf16(af[i], bf[j], acc[i][j], 0, 0, 0);
        __syncthreads();
    }

#pragma unroll
    for (int i = 0; i < 4; ++i) {
#pragma unroll
        for (int j = 0; j < 4; ++j) {
#pragma unroll
            for (int q = 0; q < 4; ++q) {
                int m = m0 + wm + i * 16 + g * 4 + q;
                int n = n0 + wn + j * 16 + r;
                if (OUT_MODE == 0) {
                    if (n < 1024) {
                        int b = m >> 12, t = m & (T_ - 1);
                        int h = n >> 6, e = n & 63;
                        Out[(((size_t)(b * H_ + h) * T_ + t) << 6) + e] = acc[i][j][q];
                    } else {
                        int c2 = n - 1024;
                        if (c2 < 32) {
                            int b = m >> 12, t = m & (T_ - 1);
                            int h = c2 & 15;
                            float v = tanhf(acc[i][j][q]) * PI_4;
                            float cc = cosf(v), ss = sinf(v);
                            int idx = (b * H_ + h) * T_ + t;
                            if (c2 < 16) { cq[idx] = cc; sq[idx] = ss; }
                            else         { ck[idx] = cc; sk[idx] = ss; }
                        }
                    }
                } else {
                    Out[(size_t)m * D_ + n] = acc[i][j][q];
                }
            }
        }
    }
}

// ---------------- chunk sums ----------------
__global__ __launch_bounds__(64) void chunk_sums(const float* __restrict__ Vt,
                                                 const float* __restrict__ ck,
                                                 const float* __restrict__ sk,
                                                 float* __restrict__ csC, float* __restrict__ csS,
                                                 float* __restrict__ kcC, float* __restrict__ kcS) {
    int blk = blockIdx.x;
    int c = blk & (NC_ - 1);
    int bh = blk >> 6;
    int e = threadIdx.x;
    const float* vbase = Vt + (((size_t)bh * T_) << 6);
    const float* ckb = ck + (size_t)bh * T_;
    const float* skb = sk + (size_t)bh * T_;
    float sc = 0.f, ss = 0.f, kc = 0.f, ks = 0.f;
    for (int i = 0; i < CS_; ++i) {
        int t = c * CS_ + i;
        float cv = ckb[t], sv = skb[t];
        float v = vbase[((size_t)t << 6) + e];
        sc = fmaf(cv, v, sc); ss = fmaf(sv, v, ss);
        kc += cv; ks += sv;
    }
    size_t oidx = ((size_t)bh * NC_ + c) * 64 + e;
    csC[oidx] = sc; csS[oidx] = ss;
    if (e == 0) { kcC[bh * NC_ + c] = kc; kcS[bh * NC_ + c] = ks; }
}

// ---------------- exclusive scan over chunks ----------------
__global__ __launch_bounds__(64) void scan_chunks(float* __restrict__ csC, float* __restrict__ csS,
                                                  float* __restrict__ kcC, float* __restrict__ kcS) {
    int bh = blockIdx.x;
    int e = threadIdx.x;
    float rc = 0.f, rs = 0.f, rkc = 0.f, rks = 0.f;
    for (int c = 0; c < NC_; ++c) {
        size_t idx = ((size_t)bh * NC_ + c) * 64 + e;
        float tc = csC[idx]; csC[idx] = rc; rc += tc;
        float ts = csS[idx]; csS[idx] = rs; rs += ts;
        if (e == 0) {
            int i2 = bh * NC_ + c;
            float a = kcC[i2]; kcC[i2] = rkc; rkc += a;
            float b2 = kcS[i2]; kcS[i2] = rks; rks += b2;
        }
    }
}

// ---------------- finalize: local cumsum, normalize, bf16 heads ----------------
__global__ __launch_bounds__(64) void finalize(const float* __restrict__ Vt,
                                               const float* __restrict__ cq, const float* __restrict__ sq,
                                               const float* __restrict__ ck, const float* __restrict__ sk,
                                               const float* __restrict__ csC, const float* __restrict__ csS,
                                               const float* __restrict__ kcC, const float* __restrict__ kcS,
                                               unsigned short* __restrict__ heads) {
    int blk = blockIdx.x;
    int c = blk & (NC_ - 1);
    int bh = blk >> 6;
    int b = bh >> 4, h = bh & 15;
    int e = threadIdx.x;
    size_t cidx = ((size_t)bh * NC_ + c) * 64 + e;
    float offc = csC[cidx], offs = csS[cidx];
    float koffc = kcC[bh * NC_ + c], koffs = kcS[bh * NC_ + c];
    const float* vbase = Vt + (((size_t)bh * T_) << 6);
    int sbase = bh * T_;
    float rc = 0.f, rs = 0.f, rkc = 0.f, rks = 0.f;
    for (int i = 0; i < CS_; ++i) {
        int t = c * CS_ + i;
        float cv = ck[sbase + t], sv = sk[sbase + t];
        float v = vbase[((size_t)t << 6) + e];
        rc = fmaf(cv, v, rc); rs = fmaf(sv, v, rs);
        rkc += cv; rks += sv;
        float cqv = cq[sbase + t], sqv = sq[sbase + t];
        float num = cqv * (offc + rc) + sqv * (offs + rs);
        float den = cqv * (koffc + rkc) + sqv * (koffs + rks) + EPS_;
        heads[(size_t)(b * T_ + t) * HD_ + h * DH_ + e] = f2bf(num / den);
    }
}

extern "C" void kernel_launch(void* const* d_in, const int* in_sizes, int n_in,
                              void* d_out, int out_size, void* d_ws, size_t ws_size,
                              hipStream_t stream) {
    const float* query = (const float*)d_in[0];
    const float* W_Q   = (const float*)d_in[1];
    const float* W_K   = (const float*)d_in[2];
    const float* W_V   = (const float*)d_in[3];
    const float* W_O   = (const float*)d_in[4];
    float* out = (float*)d_out;

    float* ws = (float*)d_ws;
    size_t off = 0;
    float* cq  = ws + off; off += (size_t)B_ * H_ * T_;          // 262144
    float* sq  = ws + off; off += (size_t)B_ * H_ * T_;
    float* ck  = ws + off; off += (size_t)B_ * H_ * T_;
    float* sk  = ws + off; off += (size_t)B_ * H_ * T_;
    float* Vt  = ws + off; off += (size_t)M_ * HD_;              // 16777216 f32
    float* csC = ws + off; off += (size_t)B_ * H_ * NC_ * DH_;
    float* csS = ws + off; off += (size_t)B_ * H_ * NC_ * DH_;
    float* kcC = ws + off; off += (size_t)B_ * H_ * NC_;
    float* kcS = ws + off; off += (size_t)B_ * H_ * NC_;
    unsigned short* us = (unsigned short*)(ws + off);
    size_t uoff = 0;
    unsigned short* Aq       = us + uoff; uoff += (size_t)M_ * D_;    // 16M bf16
    unsigned short* heads_bf = us + uoff; uoff += (size_t)M_ * HD_;   // 16M bf16
    unsigned short* Bt_v     = us + uoff; uoff += (size_t)NB_ * D_;   // 1.18M bf16
    unsigned short* Wo_bt    = us + uoff; uoff += (size_t)D_ * HD_;   // 1M bf16

    conv_a<<<dim3(M_ * D_ / 1024), 256, 0, stream>>>(query, Aq);
    conv_wv<<<dim3(HD_ * D_ / 256), 256, 0, stream>>>(W_V, Bt_v);
    conv_wqk<<<dim3(32 * D_ / 256), 256, 0, stream>>>(W_Q, W_K, Bt_v);
    conv_wo<<<dim3(D_ * HD_ / 256), 256, 0, stream>>>(W_O, Wo_bt);
    gemm_bf16<0><<<dim3(M_ / 128, 9), 256, 0, stream>>>(Aq, Bt_v, Vt, cq, sq, ck, sk);
    chunk_sums<<<dim3(B_ * H_ * NC_), 64, 0, stream>>>(Vt, ck, sk, csC, csS, kcC, kcS);
    scan_chunks<<<dim3(B_ * H_), 64, 0, stream>>>(csC, csS, kcC, kcS);
    finalize<<<dim3(B_ * H_ * NC_), 64, 0, stream>>>(Vt, cq, sq, ck, sk, csC, csS, kcC, kcS, heads_bf);
    gemm_bf16<1><<<dim3(M_ / 128, D_ / 128), 256, 0, stream>>>(heads_bf, Wo_bt, out, nullptr, nullptr, nullptr, nullptr);
}

// Round 7
// 348.981 us; speedup vs baseline: 1.8926x; 1.8926x over previous
//
#include <hip/hip_runtime.h>
#include <math.h>

#define B_ 4
#define T_ 4096
#define D_ 1024
#define H_ 16
#define DH_ 64
#define M_ (B_*T_)      // 16384
#define HD_ (H_*DH_)    // 1024
#define NB_ 1152        // B rows for gemm_v: 1024 V cols + 32 qk cols + 96 pad
#define NC_ 64
#define CS_ 64
#define PI_4 0.78539816339744830962f
#define EPS_ 1e-6f

typedef short bf16x8 __attribute__((ext_vector_type(8)));
typedef float f32x4 __attribute__((ext_vector_type(4)));

// round-to-nearest-even f32 -> bf16, no header dependency
static __device__ __forceinline__ unsigned short f2bf(float f) {
    unsigned u = __builtin_bit_cast(unsigned, f);
    unsigned rounding = 0x7fffu + ((u >> 16) & 1u);
    return (unsigned short)((u + rounding) >> 16);
}

#define GLDS16(gsrc, ldst) \
    __builtin_amdgcn_global_load_lds((const __attribute__((address_space(1))) void*)(gsrc), \
                                     (__attribute__((address_space(3))) void*)(ldst), 16, 0, 0)

// ---------------- converts ----------------
__global__ __launch_bounds__(256) void conv_a(const float* __restrict__ in,
                                              unsigned short* __restrict__ out) {
    int i = blockIdx.x * 256 + threadIdx.x;          // over 4M float4s
    float4 v = ((const float4*)in)[i];
    ushort4 o;
    o.x = f2bf(v.x); o.y = f2bf(v.y); o.z = f2bf(v.z); o.w = f2bf(v.w);
    ((ushort4*)out)[i] = o;
}

// Wv_bt[(h*64+e)*1024 + k] = WV[h*65536 + k*64 + e]   (rows 0..1023)
__global__ __launch_bounds__(256) void conv_wv(const float* __restrict__ WV,
                                               unsigned short* __restrict__ Bt) {
    int f = blockIdx.x * 256 + threadIdx.x;          // 1M
    int n = f >> 10, k = f & 1023;
    int h = n >> 6, e = n & 63;
    Bt[f] = f2bf(WV[h * 65536 + k * 64 + e]);
}

// rows 1024..1055 of Bt_v: 16 W_Q columns then 16 W_K columns
__global__ __launch_bounds__(256) void conv_wqk(const float* __restrict__ WQ,
                                                const float* __restrict__ WK,
                                                unsigned short* __restrict__ Bt) {
    int f = blockIdx.x * 256 + threadIdx.x;          // 32K
    int row = f >> 10, k = f & 1023;
    float v = (row < 16) ? WQ[row * 1024 + k] : WK[(row - 16) * 1024 + k];
    Bt[(size_t)(1024 + row) * 1024 + k] = f2bf(v);
}

// Wo_bt[d*1024 + h*64 + e] = WO[d*1024 + e*16 + h]
__global__ __launch_bounds__(256) void conv_wo(const float* __restrict__ WO,
                                               unsigned short* __restrict__ Bt) {
    int f = blockIdx.x * 256 + threadIdx.x;          // 1M
    int d = f >> 10, rem = f & 1023;
    int h = rem >> 6, e = rem & 63;
    Bt[f] = f2bf(WO[d * 1024 + e * 16 + h]);
}

// ---------------- bf16 MFMA GEMM core (m97 structure) ----------------
// C = A[M,K=1024] x B (Bt[n][k] transposed layout), 128x128 tile, BK=32.
// OUT_MODE 0: n<1024 -> Vt[b,h,t,e]; 1024<=n<1056 -> RAW acc -> qkraw[m*32+(n-1024)].
// OUT_MODE 1: store to Out[m*1024+n].
template <int OUT_MODE>
__global__ __launch_bounds__(256) void gemm_bf16(const unsigned short* __restrict__ A,
                                                 const unsigned short* __restrict__ Bt,
                                                 float* __restrict__ Out,
                                                 float* __restrict__ qkraw) {
    __shared__ short As[128 * 32];
    __shared__ short Bs[128 * 32];
    const int K = 1024;
    int tid = threadIdx.x;
    int m0 = blockIdx.x * 128;
    int n0 = blockIdx.y * 128;
    int lane = tid & 63, w = tid >> 6;
    int wm = (w >> 1) * 64, wn = (w & 1) * 64;
    int r = lane & 15, g = lane >> 4;

    int srow = tid >> 2;            // 0..63 staged row within a round
    int skq  = (tid & 3) * 8;       // k offset (8 bf16 = 16B)

    f32x4 acc[4][4];
#pragma unroll
    for (int i = 0; i < 4; ++i)
#pragma unroll
        for (int j = 0; j < 4; ++j) acc[i][j] = (f32x4)0.f;

    const unsigned short* gA = A  + (size_t)(m0 + srow) * K + skq;
    const unsigned short* gB = Bt + (size_t)(n0 + srow) * K + skq;
    char* lA = (char*)As + tid * 16;
    char* lB = (char*)Bs + tid * 16;

    for (int k0 = 0; k0 < K; k0 += 32) {
        GLDS16(gA + k0,            lA);
        GLDS16(gA + k0 + 64 * K,   lA + 4096);
        GLDS16(gB + k0,            lB);
        GLDS16(gB + k0 + 64 * K,   lB + 4096);
        __syncthreads();

        bf16x8 af[4], bf[4];
#pragma unroll
        for (int i = 0; i < 4; ++i)
            af[i] = *(const bf16x8*)&As[(wm + i * 16 + r) * 32 + g * 8];
#pragma unroll
        for (int j = 0; j < 4; ++j)
            bf[j] = *(const bf16x8*)&Bs[(wn + j * 16 + r) * 32 + g * 8];
#pragma unroll
        for (int i = 0; i < 4; ++i)
#pragma unroll
            for (int j = 0; j < 4; ++j)
                acc[i][j] = __builtin_amdgcn_mfma_f32_16x16x32_bf16(af[i], bf[j], acc[i][j], 0, 0, 0);
        __syncthreads();
    }

#pragma unroll
    for (int i = 0; i < 4; ++i) {
#pragma unroll
        for (int j = 0; j < 4; ++j) {
#pragma unroll
            for (int q = 0; q < 4; ++q) {
                int m = m0 + wm + i * 16 + g * 4 + q;
                int n = n0 + wn + j * 16 + r;
                if (OUT_MODE == 0) {
                    if (n < 1024) {
                        int b = m >> 12, t = m & (T_ - 1);
                        int h = n >> 6, e = n & 63;
                        Out[(((size_t)(b * H_ + h) * T_ + t) << 6) + e] = acc[i][j][q];
                    } else {
                        int c2 = n - 1024;
                        if (c2 < 32) qkraw[(size_t)m * 32 + c2] = acc[i][j][q];
                    }
                } else {
                    Out[(size_t)m * D_ + n] = acc[i][j][q];
                }
            }
        }
    }
}

// ---------------- qk_post: tanh/cos/sin from raw projections ----------------
// f enumerates (b,h,t); reads qkraw[m][h], qkraw[m][16+h]; writes coalesced.
__global__ __launch_bounds__(256) void qk_post(const float* __restrict__ qkraw,
                                               float* __restrict__ cq, float* __restrict__ sq,
                                               float* __restrict__ ck, float* __restrict__ sk) {
    int f = blockIdx.x * 256 + threadIdx.x;          // over B_*H_*T_ = 262144
    int t = f & (T_ - 1);
    int h = (f >> 12) & 15;
    int b = f >> 16;
    size_t m = (size_t)b * T_ + t;
    float aq = qkraw[m * 32 + h];
    float ak = qkraw[m * 32 + 16 + h];
    float vq = tanhf(aq) * PI_4;
    float vk = tanhf(ak) * PI_4;
    cq[f] = cosf(vq); sq[f] = sinf(vq);
    ck[f] = cosf(vk); sk[f] = sinf(vk);
}

// ---------------- chunk sums ----------------
__global__ __launch_bounds__(64) void chunk_sums(const float* __restrict__ Vt,
                                                 const float* __restrict__ ck,
                                                 const float* __restrict__ sk,
                                                 float* __restrict__ csC, float* __restrict__ csS,
                                                 float* __restrict__ kcC, float* __restrict__ kcS) {
    int blk = blockIdx.x;
    int c = blk & (NC_ - 1);
    int bh = blk >> 6;
    int e = threadIdx.x;
    const float* vbase = Vt + (((size_t)bh * T_) << 6);
    const float* ckb = ck + (size_t)bh * T_;
    const float* skb = sk + (size_t)bh * T_;
    float sc = 0.f, ss = 0.f, kc = 0.f, ks = 0.f;
    for (int i = 0; i < CS_; ++i) {
        int t = c * CS_ + i;
        float cv = ckb[t], sv = skb[t];
        float v = vbase[((size_t)t << 6) + e];
        sc = fmaf(cv, v, sc); ss = fmaf(sv, v, ss);
        kc += cv; ks += sv;
    }
    size_t oidx = ((size_t)bh * NC_ + c) * 64 + e;
    csC[oidx] = sc; csS[oidx] = ss;
    if (e == 0) { kcC[bh * NC_ + c] = kc; kcS[bh * NC_ + c] = ks; }
}

// ---------------- exclusive scan over chunks ----------------
__global__ __launch_bounds__(64) void scan_chunks(float* __restrict__ csC, float* __restrict__ csS,
                                                  float* __restrict__ kcC, float* __restrict__ kcS) {
    int bh = blockIdx.x;
    int e = threadIdx.x;
    float rc = 0.f, rs = 0.f, rkc = 0.f, rks = 0.f;
    for (int c = 0; c < NC_; ++c) {
        size_t idx = ((size_t)bh * NC_ + c) * 64 + e;
        float tc = csC[idx]; csC[idx] = rc; rc += tc;
        float ts = csS[idx]; csS[idx] = rs; rs += ts;
        if (e == 0) {
            int i2 = bh * NC_ + c;
            float a = kcC[i2]; kcC[i2] = rkc; rkc += a;
            float b2 = kcS[i2]; kcS[i2] = rks; rks += b2;
        }
    }
}

// ---------------- finalize: local cumsum, normalize, bf16 heads ----------------
__global__ __launch_bounds__(64) void finalize(const float* __restrict__ Vt,
                                               const float* __restrict__ cq, const float* __restrict__ sq,
                                               const float* __restrict__ ck, const float* __restrict__ sk,
                                               const float* __restrict__ csC, const float* __restrict__ csS,
                                               const float* __restrict__ kcC, const float* __restrict__ kcS,
                                               unsigned short* __restrict__ heads) {
    int blk = blockIdx.x;
    int c = blk & (NC_ - 1);
    int bh = blk >> 6;
    int b = bh >> 4, h = bh & 15;
    int e = threadIdx.x;
    size_t cidx = ((size_t)bh * NC_ + c) * 64 + e;
    float offc = csC[cidx], offs = csS[cidx];
    float koffc = kcC[bh * NC_ + c], koffs = kcS[bh * NC_ + c];
    const float* vbase = Vt + (((size_t)bh * T_) << 6);
    int sbase = bh * T_;
    float rc = 0.f, rs = 0.f, rkc = 0.f, rks = 0.f;
    for (int i = 0; i < CS_; ++i) {
        int t = c * CS_ + i;
        float cv = ck[sbase + t], sv = sk[sbase + t];
        float v = vbase[((size_t)t << 6) + e];
        rc = fmaf(cv, v, rc); rs = fmaf(sv, v, rs);
        rkc += cv; rks += sv;
        float cqv = cq[sbase + t], sqv = sq[sbase + t];
        float num = cqv * (offc + rc) + sqv * (offs + rs);
        float den = cqv * (koffc + rkc) + sqv * (koffs + rks) + EPS_;
        heads[(size_t)(b * T_ + t) * HD_ + h * DH_ + e] = f2bf(num / den);
    }
}

extern "C" void kernel_launch(void* const* d_in, const int* in_sizes, int n_in,
                              void* d_out, int out_size, void* d_ws, size_t ws_size,
                              hipStream_t stream) {
    const float* query = (const float*)d_in[0];
    const float* W_Q   = (const float*)d_in[1];
    const float* W_K   = (const float*)d_in[2];
    const float* W_V   = (const float*)d_in[3];
    const float* W_O   = (const float*)d_in[4];
    float* out = (float*)d_out;

    float* ws = (float*)d_ws;
    size_t off = 0;
    float* cq    = ws + off; off += (size_t)B_ * H_ * T_;        // 262144
    float* sq    = ws + off; off += (size_t)B_ * H_ * T_;
    float* ck    = ws + off; off += (size_t)B_ * H_ * T_;
    float* sk    = ws + off; off += (size_t)B_ * H_ * T_;
    float* Vt    = ws + off; off += (size_t)M_ * HD_;            // 16777216 f32
    float* qkraw = ws + off; off += (size_t)M_ * 32;             // 524288 f32
    float* csC   = ws + off; off += (size_t)B_ * H_ * NC_ * DH_;
    float* csS   = ws + off; off += (size_t)B_ * H_ * NC_ * DH_;
    float* kcC   = ws + off; off += (size_t)B_ * H_ * NC_;
    float* kcS   = ws + off; off += (size_t)B_ * H_ * NC_;
    unsigned short* us = (unsigned short*)(ws + off);
    size_t uoff = 0;
    unsigned short* Aq       = us + uoff; uoff += (size_t)M_ * D_;    // 16M bf16
    unsigned short* heads_bf = us + uoff; uoff += (size_t)M_ * HD_;   // 16M bf16
    unsigned short* Bt_v     = us + uoff; uoff += (size_t)NB_ * D_;   // 1.18M bf16
    unsigned short* Wo_bt    = us + uoff; uoff += (size_t)D_ * HD_;   // 1M bf16

    conv_a<<<dim3(M_ * D_ / 1024), 256, 0, stream>>>(query, Aq);
    conv_wv<<<dim3(HD_ * D_ / 256), 256, 0, stream>>>(W_V, Bt_v);
    conv_wqk<<<dim3(32 * D_ / 256), 256, 0, stream>>>(W_Q, W_K, Bt_v);
    conv_wo<<<dim3(D_ * HD_ / 256), 256, 0, stream>>>(W_O, Wo_bt);
    gemm_bf16<0><<<dim3(M_ / 128, 9), 256, 0, stream>>>(Aq, Bt_v, Vt, qkraw);
    qk_post<<<dim3(B_ * H_ * T_ / 256), 256, 0, stream>>>(qkraw, cq, sq, ck, sk);
    chunk_sums<<<dim3(B_ * H_ * NC_), 64, 0, stream>>>(Vt, ck, sk, csC, csS, kcC, kcS);
    scan_chunks<<<dim3(B_ * H_), 64, 0, stream>>>(csC, csS, kcC, kcS);
    finalize<<<dim3(B_ * H_ * NC_), 64, 0, stream>>>(Vt, cq, sq, ck, sk, csC, csS, kcC, kcS, heads_bf);
    gemm_bf16<1><<<dim3(M_ / 128, D_ / 128), 256, 0, stream>>>(heads_bf, Wo_bt, out, nullptr);
}